// Round 2
// baseline (2221.309 us; speedup 1.0000x reference)
//
#include <hip/hip_runtime.h>
#include <hip/hip_bf16.h>
#include <stdint.h>

typedef unsigned short u16;
typedef unsigned int u32;

// ---- problem constants ----
#define BDIM   4
#define CDIM   256
#define HDIM   128
#define WDIM   128
#define NPIX   (HDIM*WDIM)        // 16384
#define HEADS  8
#define DH     32
#define BLK    8
#define HALO   3
#define WINSZ  14
#define NKEY   196
#define NB     256                // 16x16 blocks per image
#define QKSCALE 0.17677669529663689f   // 32^-0.5

// ---- workspace layout (bytes) ----
#define WS_XC   ((size_t)0)                       // canon x bf16 (B,C,H,W): 33,554,432 B
#define WS_WQ   ((size_t)33554432)                // w_q fp32: 262,144 B
#define WS_WKV  (WS_WQ + 262144)                  // w_kv fp32: 524,288 B
#define WS_FCW  (WS_WKV + 524288)                 // fc_w fp32: 262,144 B
#define WS_FCB  (WS_FCW + 262144)                 // fc_b fp32: 1,024 B
#define WS_RH   (WS_FCB + 1024)                   // rel_h fp32: 3,456 B
#define WS_RW   (WS_RH + 3456)                    // rel_w fp32: 3,456 B
#define WS_FLAG (WS_RW + 3456)                    // int flag
#define WS_Q    ((size_t)34611200)                // q bf16 (B, pix, C): 33,554,432 B
#define WS_KV   (WS_Q + 33554432)                 // kv bf16 (B, pix, 2C): 67,108,864 B
#define WS_CTX  (WS_KV + 67108864)                // ctx bf16 (B, nb, 64, C): 33,554,432 B
// total ≈ 168.8 MB

__device__ __forceinline__ float bflo(u32 u){ return __uint_as_float(u << 16); }
__device__ __forceinline__ float bfhi(u32 u){ return __uint_as_float(u & 0xffff0000u); }
__device__ __forceinline__ float bf2f(u16 h){ return __uint_as_float(((u32)h) << 16); }
__device__ __forceinline__ u16 f2bf(float f){
    u32 u = __float_as_uint(f);
    u32 r = (u + 0x7fffu + ((u >> 16) & 1u)) >> 16;   // RNE
    return (u16)r;
}

// ---------------- dtype detector ----------------
// If input is fp32, even 16-bit halves are mantissa bits -> wild exponents as bf16.
__global__ void k_detect(const u16* __restrict__ x, int* __restrict__ flag){
    int t = threadIdx.x;
    int wild = 0;
    for (int i = t; i < 1024; i += 64){
        u16 u = x[2*i];
        int ef = (u >> 7) & 0xff;
        if (ef >= 0x90) wild = 1;
    }
    int any = __any(wild);
    if (t == 0) *flag = any ? 1 : 0;
}

// ---------------- canonicalize x -> bf16 ----------------
__global__ void k_canon_x(const void* __restrict__ src, u16* __restrict__ dst,
                          const int* __restrict__ flag){
    const int isf = *flag;
    size_t i = (size_t)blockIdx.x * blockDim.x + threadIdx.x;   // 2,097,152 threads
    size_t base = i * 8;
    if (isf){
        const float4* s = (const float4*)src;
        float4 a = s[i*2+0];
        float4 b = s[i*2+1];
        u32 pk[4];
        pk[0] = (u32)f2bf(a.x) | ((u32)f2bf(a.y) << 16);
        pk[1] = (u32)f2bf(a.z) | ((u32)f2bf(a.w) << 16);
        pk[2] = (u32)f2bf(b.x) | ((u32)f2bf(b.y) << 16);
        pk[3] = (u32)f2bf(b.z) | ((u32)f2bf(b.w) << 16);
        *(uint4*)(dst + base) = *(uint4*)pk;
    } else {
        const uint4* s = (const uint4*)src;
        *(uint4*)(dst + base) = s[i];
    }
}

// ---------------- canonicalize small tensors -> fp32 ----------------
__global__ void k_canon_f(const void* __restrict__ src, float* __restrict__ dst, int n,
                          const int* __restrict__ flag){
    const int isf = *flag;
    int i = blockIdx.x * 256 + threadIdx.x;
    if (i < n){
        dst[i] = isf ? ((const float*)src)[i] : bf2f(((const u16*)src)[i]);
    }
}

// ---------------- QKV projection ----------------
// q[pix][o<256], kv[pix][o-256] = sum_c w[o][c] * x[c][pix]
// block tile: 128 o x 64 px, k-chunks of 64; thread = 8 o x 4 px
__global__ __launch_bounds__(256, 2)
void k_proj(const u16* __restrict__ xc, const float* __restrict__ wq,
            const float* __restrict__ wkv, u16* __restrict__ qo, u16* __restrict__ kvo){
    __shared__ u16  xs[256][64];     // [c][px]  32 KB
    __shared__ float wt[64][132];    // [c][o]   33.8 KB (pad 132 -> b128-aligned rows)
    const int t = threadIdx.x;
    const int b = blockIdx.z, h = blockIdx.y;
    const int px0 = blockIdx.x * 64;

    // stage x tile (coalesced along px, [c][px] layout, no transpose needed)
    {
        const u32* xu = (const u32*)xc;
        const size_t rowbase = ((size_t)b * 4194304 + (size_t)h * 128 + px0) >> 1;
        u32* xsu = (u32*)xs;
        #pragma unroll
        for (int rep = 0; rep < 32; ++rep){
            int f = rep * 256 + t;
            int c = f >> 5, pu = f & 31;
            xsu[c * 32 + pu] = xu[rowbase + (size_t)c * 8192 + pu];
        }
    }
    const int og = t >> 4;   // 16 groups of 8 o
    const int pg = t & 15;   // 16 groups of 4 px

    for (int ot = 0; ot < 6; ++ot){
        const int o0 = ot * 128;
        float acc[8][4];
        #pragma unroll
        for (int j = 0; j < 8; ++j)
            #pragma unroll
            for (int p = 0; p < 4; ++p) acc[j][p] = 0.f;

        for (int kc = 0; kc < 4; ++kc){
            const int c0 = kc * 64;
            __syncthreads();
            // stage weights (fp32) for this (o-tile, k-chunk)
            #pragma unroll
            for (int i = 0; i < 32; ++i){
                int f = i * 256 + t;
                int cl = f & 63, ol = f >> 6;
                int o = o0 + ol;
                float wv;
                if (o < 256) wv = wq[o * 256 + c0 + cl];
                else         wv = wkv[(o - 256) * 256 + c0 + cl];
                wt[cl][ol] = wv;
            }
            __syncthreads();
            #pragma unroll 8
            for (int c = 0; c < 64; ++c){
                const float4 w0 = *(const float4*)&wt[c][og * 8];
                const float4 w1 = *(const float4*)&wt[c][og * 8 + 4];
                const uint2  xv = *(const uint2*)&xs[c0 + c][pg * 4];
                float wv[8] = {w0.x, w0.y, w0.z, w0.w, w1.x, w1.y, w1.z, w1.w};
                float xf[4] = {bflo(xv.x), bfhi(xv.x), bflo(xv.y), bfhi(xv.y)};
                #pragma unroll
                for (int j = 0; j < 8; ++j)
                    #pragma unroll
                    for (int p = 0; p < 4; ++p)
                        acc[j][p] = fmaf(wv[j], xf[p], acc[j][p]);
            }
        }
        // store: 8 consecutive o per px -> one uint4 (8 bf16)
        #pragma unroll
        for (int p = 0; p < 4; ++p){
            const int px = px0 + pg * 4 + p;
            const size_t pix = (size_t)b * 16384 + (size_t)h * 128 + px;
            u32 pk[4];
            #pragma unroll
            for (int d = 0; d < 4; ++d)
                pk[d] = (u32)f2bf(acc[2*d][p]) | ((u32)f2bf(acc[2*d+1][p]) << 16);
            if (o0 < 256)
                *(uint4*)(qo + pix * 256 + o0 + og * 8) = *(uint4*)pk;
            else
                *(uint4*)(kvo + pix * 512 + (o0 - 256) + og * 8) = *(uint4*)pk;
        }
    }
}

// ---------------- halo attention ----------------
// one thread per (query, head); wave = one head (uniform LDS reads)
// online softmax over 196 keys, staged 28 px (2 window rows) at a time
// __launch_bounds__(512, 2): 2 waves/EU -> up to 256 VGPRs/wave. Live state is
// qv[32]+o[32]+bw[14]+bh[14]+temps ~ 160 VGPRs; the default 128-reg budget
// spilled to scratch (rocprof R1: WRITE_SIZE 1.77 GB vs 33.5 MB ideal).
#define DOT8(u4, B) \
    s = fmaf(qv[B+0], bflo(u4.x), s); s = fmaf(qv[B+1], bfhi(u4.x), s); \
    s = fmaf(qv[B+2], bflo(u4.y), s); s = fmaf(qv[B+3], bfhi(u4.y), s); \
    s = fmaf(qv[B+4], bflo(u4.z), s); s = fmaf(qv[B+5], bfhi(u4.z), s); \
    s = fmaf(qv[B+6], bflo(u4.w), s); s = fmaf(qv[B+7], bfhi(u4.w), s);

#define VACC8(u4, B) \
    o[B+0] = fmaf(o[B+0], al, p * bflo(u4.x)); o[B+1] = fmaf(o[B+1], al, p * bfhi(u4.x)); \
    o[B+2] = fmaf(o[B+2], al, p * bflo(u4.y)); o[B+3] = fmaf(o[B+3], al, p * bfhi(u4.y)); \
    o[B+4] = fmaf(o[B+4], al, p * bflo(u4.z)); o[B+5] = fmaf(o[B+5], al, p * bfhi(u4.z)); \
    o[B+6] = fmaf(o[B+6], al, p * bflo(u4.w)); o[B+7] = fmaf(o[B+7], al, p * bfhi(u4.w));

__global__ __launch_bounds__(512, 2)
void k_attn(const u16* __restrict__ qc, const u16* __restrict__ kvc,
            const float* __restrict__ rh, const float* __restrict__ rw,
            u16* __restrict__ ctx){
    __shared__ u16 kvs[28][512];   // 28 KB
    const int t = threadIdx.x;
    const int head = t >> 6, lane = t & 63;
    const int qx = lane >> 3, qy = lane & 7;
    const int blk = blockIdx.x, b = blockIdx.y;
    const int r0 = (blk >> 4) * 8, c0 = (blk & 15) * 8;

    // load q vector (32 ch) for this (query, head)
    float qv[32];
    {
        const size_t base = ((size_t)b * 16384 + (size_t)(r0 + qx) * 128 + (c0 + qy)) * 256
                            + head * 32;
        const uint4* qp = (const uint4*)(qc + base);
        #pragma unroll
        for (int i = 0; i < 4; ++i){
            uint4 u = qp[i];
            qv[i*8+0] = bflo(u.x); qv[i*8+1] = bfhi(u.x);
            qv[i*8+2] = bflo(u.y); qv[i*8+3] = bfhi(u.y);
            qv[i*8+4] = bflo(u.z); qv[i*8+5] = bfhi(u.z);
            qv[i*8+6] = bflo(u.w); qv[i*8+7] = bfhi(u.w);
        }
    }
    // relative position biases: bw[j] = q . rel_w[j - qy + 13], bh[i] = q . rel_h[i - qx + 13]
    float bw_[14], bh_[14];
    #pragma unroll
    for (int j = 0; j < 14; ++j){
        const float* r = rw + (j - qy + 13) * 32;
        float s = 0.f;
        #pragma unroll
        for (int d = 0; d < 32; ++d) s = fmaf(qv[d], r[d], s);
        bw_[j] = s;
    }
    #pragma unroll
    for (int i = 0; i < 14; ++i){
        const float* r = rh + (i - qx + 13) * 32;
        float s = 0.f;
        #pragma unroll
        for (int d = 0; d < 32; ++d) s = fmaf(qv[d], r[d], s);
        bh_[i] = s;
    }

    float m = -1e30f, l = 0.f;
    float o[32];
    #pragma unroll
    for (int d = 0; d < 32; ++d) o[d] = 0.f;

    for (int tile = 0; tile < 7; ++tile){
        __syncthreads();
        // stage 28 window pixels x 512 ch (zero-fill OOB: reference zero-pads, keys stay in softmax)
        #pragma unroll
        for (int rep = 0; rep < 14; ++rep){
            int fu = rep * 512 + t;
            int pl = fu >> 8, chu = fu & 255;
            int hh = r0 - 3 + tile * 2 + pl / 14;
            int ww = c0 - 3 + pl % 14;
            u32 val = 0;
            if (hh >= 0 && hh < 128 && ww >= 0 && ww < 128)
                val = ((const u32*)kvc)[((size_t)b * 16384 + hh * 128 + ww) * 256 + chu];
            ((u32*)kvs)[pl * 256 + chu] = val;
        }
        __syncthreads();
        const float bh0 = bh_[2 * tile], bh1 = bh_[2 * tile + 1];
        #pragma unroll
        for (int kk = 0; kk < 28; ++kk){
            const int jj = kk % 14;                       // static (loop unrolled)
            const uint4* kp = (const uint4*)(&kvs[kk][head * 32]);
            float s = 0.f;
            { uint4 u = kp[0]; DOT8(u, 0)  }
            { uint4 u = kp[1]; DOT8(u, 8)  }
            { uint4 u = kp[2]; DOT8(u, 16) }
            { uint4 u = kp[3]; DOT8(u, 24) }
            s = fmaf(s, QKSCALE, bw_[jj] + ((kk < 14) ? bh0 : bh1));
            const float mn = fmaxf(m, s);
            const float al = __expf(m - mn);
            const float p  = __expf(s - mn);
            l = fmaf(l, al, p);
            const uint4* vp = (const uint4*)(&kvs[kk][256 + head * 32]);
            { uint4 u = vp[0]; VACC8(u, 0)  }
            { uint4 u = vp[1]; VACC8(u, 8)  }
            { uint4 u = vp[2]; VACC8(u, 16) }
            { uint4 u = vp[3]; VACC8(u, 24) }
            m = mn;
        }
    }
    const float inv = 1.f / l;
    const size_t cbase = ((size_t)(b * 256 + blk) * 64 + lane) * 256 + head * 32;
    #pragma unroll
    for (int i = 0; i < 4; ++i){
        u32 pk[4];
        #pragma unroll
        for (int d = 0; d < 4; ++d)
            pk[d] = (u32)f2bf(o[i*8+2*d] * inv) | ((u32)f2bf(o[i*8+2*d+1] * inv) << 16);
        *(uint4*)(ctx + cbase + i * 8) = *(uint4*)pk;
    }
}

// ---------------- output projection + bias ----------------
// out[b,o,h,w] = sum_c ctx[pix][c] * fcw[o][c] + fcb[o]
__global__ __launch_bounds__(256, 2)
void k_out(const u16* __restrict__ ctx, const float* __restrict__ fcw,
           const float* __restrict__ fcb, void* __restrict__ outp,
           const int* __restrict__ flag){
    __shared__ u16  xs[256][68];    // [c][px], padded (34.8 KB)
    __shared__ float wt[64][132];   // 33.8 KB
    const int t = threadIdx.x;
    const int b = blockIdx.z, h = blockIdx.y;
    const int px0 = blockIdx.x * 64;

    // stage ctx tile, transposing pixel-major -> [c][px]
    {
        #pragma unroll
        for (int rep = 0; rep < 32; ++rep){
            int fu = rep * 256 + t;
            int pxl = fu >> 7, chu = fu & 127;
            int px = px0 + pxl;
            int blkid = (h >> 3) * 16 + (px >> 3);
            int qi = (h & 7) * 8 + (px & 7);
            u32 v = ((const u32*)ctx)[(((size_t)b * 256 + blkid) * 64 + qi) * 128 + chu];
            xs[2*chu][pxl]     = (u16)(v & 0xffffu);
            xs[2*chu + 1][pxl] = (u16)(v >> 16);
        }
    }
    const int og = t >> 4, pg = t & 15;
    const int isf32 = *flag;

    for (int ot = 0; ot < 2; ++ot){
        const int o0 = ot * 128;
        float acc[8][4];
        #pragma unroll
        for (int j = 0; j < 8; ++j)
            #pragma unroll
            for (int p = 0; p < 4; ++p) acc[j][p] = 0.f;

        for (int kc = 0; kc < 4; ++kc){
            const int c0 = kc * 64;
            __syncthreads();
            #pragma unroll
            for (int i = 0; i < 32; ++i){
                int f = i * 256 + t;
                int cl = f & 63, ol = f >> 6;
                wt[cl][ol] = fcw[(o0 + ol) * 256 + c0 + cl];
            }
            __syncthreads();
            #pragma unroll 8
            for (int c = 0; c < 64; ++c){
                const float4 w0 = *(const float4*)&wt[c][og * 8];
                const float4 w1 = *(const float4*)&wt[c][og * 8 + 4];
                const uint2  xv = *(const uint2*)&xs[c0 + c][pg * 4];
                float wv[8] = {w0.x, w0.y, w0.z, w0.w, w1.x, w1.y, w1.z, w1.w};
                float xf[4] = {bflo(xv.x), bfhi(xv.x), bflo(xv.y), bfhi(xv.y)};
                #pragma unroll
                for (int j = 0; j < 8; ++j)
                    #pragma unroll
                    for (int p = 0; p < 4; ++p)
                        acc[j][p] = fmaf(wv[j], xf[p], acc[j][p]);
            }
        }
        #pragma unroll
        for (int j = 0; j < 8; ++j){
            const int oo = o0 + og * 8 + j;
            const float bias = fcb[oo];
            const size_t obase = ((size_t)b * 256 + oo) * 16384 + (size_t)h * 128 + px0 + pg * 4;
            if (isf32){
                float4 v;
                v.x = acc[j][0] + bias; v.y = acc[j][1] + bias;
                v.z = acc[j][2] + bias; v.w = acc[j][3] + bias;
                *(float4*)((float*)outp + obase) = v;
            } else {
                u32 pk0 = (u32)f2bf(acc[j][0] + bias) | ((u32)f2bf(acc[j][1] + bias) << 16);
                u32 pk1 = (u32)f2bf(acc[j][2] + bias) | ((u32)f2bf(acc[j][3] + bias) << 16);
                uint2 v; v.x = pk0; v.y = pk1;
                *(uint2*)((u16*)outp + obase) = v;
            }
        }
    }
}

extern "C" void kernel_launch(void* const* d_in, const int* in_sizes, int n_in,
                              void* d_out, int out_size, void* d_ws, size_t ws_size,
                              hipStream_t stream){
    const void* x    = d_in[0];
    const void* wq   = d_in[1];
    const void* wkv  = d_in[2];
    const void* fcw  = d_in[3];
    const void* fcb  = d_in[4];
    const void* relh = d_in[5];
    const void* relw = d_in[6];

    char* ws = (char*)d_ws;
    u16*   xc   = (u16*)(ws + WS_XC);
    float* wqf  = (float*)(ws + WS_WQ);
    float* wkvf = (float*)(ws + WS_WKV);
    float* fcwf = (float*)(ws + WS_FCW);
    float* fcbf = (float*)(ws + WS_FCB);
    float* rhf  = (float*)(ws + WS_RH);
    float* rwf  = (float*)(ws + WS_RW);
    int*   flag = (int*)(ws + WS_FLAG);
    u16*   qb   = (u16*)(ws + WS_Q);
    u16*   kvb  = (u16*)(ws + WS_KV);
    u16*   ctxb = (u16*)(ws + WS_CTX);

    k_detect<<<1, 64, 0, stream>>>((const u16*)x, flag);
    k_canon_x<<<8192, 256, 0, stream>>>(x, xc, flag);
    k_canon_f<<<256, 256, 0, stream>>>(wq,   wqf,  65536,  flag);
    k_canon_f<<<512, 256, 0, stream>>>(wkv,  wkvf, 131072, flag);
    k_canon_f<<<256, 256, 0, stream>>>(fcw,  fcwf, 65536,  flag);
    k_canon_f<<<1,   256, 0, stream>>>(fcb,  fcbf, 256,    flag);
    k_canon_f<<<4,   256, 0, stream>>>(relh, rhf,  864,    flag);
    k_canon_f<<<4,   256, 0, stream>>>(relw, rwf,  864,    flag);

    dim3 gp(2, 128, 4);
    k_proj<<<gp, 256, 0, stream>>>(xc, wqf, wkvf, qb, kvb);
    dim3 ga(256, 4);
    k_attn<<<ga, 512, 0, stream>>>(qb, kvb, rhf, rwf, ctxb);
    dim3 go(2, 128, 4);
    k_out<<<go, 256, 0, stream>>>(ctxb, fcwf, fcbf, d_out, flag);
}

// Round 4
// 1041.336 us; speedup vs baseline: 2.1331x; 2.1331x over previous
//
#include <hip/hip_runtime.h>
#include <hip/hip_bf16.h>
#include <stdint.h>

typedef unsigned short u16;
typedef unsigned int u32;

// ---- problem constants ----
#define BDIM   4
#define CDIM   256
#define HDIM   128
#define WDIM   128
#define HEADS  8
#define DH     32
#define BLK    8
#define HALO   3
#define WINSZ  14
#define NB     256
#define QKSCALE 0.17677669529663689f   // 32^-0.5

// ---- workspace layout (bytes) ----
#define WS_XC   ((size_t)0)
#define WS_WQ   ((size_t)33554432)
#define WS_WKV  (WS_WQ + 262144)
#define WS_FCW  (WS_WKV + 524288)
#define WS_FCB  (WS_FCW + 262144)
#define WS_RH   (WS_FCB + 1024)
#define WS_RW   (WS_RH + 3456)
#define WS_FLAG (WS_RW + 3456)
#define WS_Q    ((size_t)34611200)
#define WS_KV   (WS_Q + 33554432)
#define WS_CTX  (WS_KV + 67108864)

typedef float f32x4 __attribute__((ext_vector_type(4)));
typedef short s16x8 __attribute__((ext_vector_type(8)));
typedef short s16x4 __attribute__((ext_vector_type(4)));

__device__ __forceinline__ float bflo(u32 u){ return __uint_as_float(u << 16); }
__device__ __forceinline__ float bfhi(u32 u){ return __uint_as_float(u & 0xffff0000u); }
__device__ __forceinline__ float bf2f(u16 h){ return __uint_as_float(((u32)h) << 16); }
__device__ __forceinline__ u16 f2bf(float f){
    u32 u = __float_as_uint(f);
    u32 r = (u + 0x7fffu + ((u >> 16) & 1u)) >> 16;   // RNE
    return (u16)r;
}

// K=16 bf16 MFMA. NOTE: __has_builtin guards on amdgcn builtins must live
// inside __HIP_DEVICE_COMPILE__ — the host pass parses device bodies and
// picks the wrong branch otherwise (R3 compile failure).
#if defined(__HIP_DEVICE_COMPILE__)
__device__ __forceinline__ f32x4 mfma16(s16x4 a, s16x4 b, f32x4 c){
    return __builtin_amdgcn_mfma_f32_16x16x16bf16_1k(a, b, c, 0, 0, 0);
}
#else
__device__ __forceinline__ f32x4 mfma16(s16x4 a, s16x4 b, f32x4 c){ return c; }
#endif

// ---------------- dtype detector ----------------
__global__ void k_detect(const u16* __restrict__ x, int* __restrict__ flag){
    int t = threadIdx.x;
    int wild = 0;
    for (int i = t; i < 1024; i += 64){
        u16 u = x[2*i];
        int ef = (u >> 7) & 0xff;
        if (ef >= 0x90) wild = 1;
    }
    int any = __any(wild);
    if (t == 0) *flag = any ? 1 : 0;
}

// ---------------- canonicalize x -> bf16 ----------------
__global__ void k_canon_x(const void* __restrict__ src, u16* __restrict__ dst,
                          const int* __restrict__ flag){
    const int isf = *flag;
    size_t i = (size_t)blockIdx.x * blockDim.x + threadIdx.x;
    size_t base = i * 8;
    if (isf){
        const float4* s = (const float4*)src;
        float4 a = s[i*2+0];
        float4 b = s[i*2+1];
        u32 pk[4];
        pk[0] = (u32)f2bf(a.x) | ((u32)f2bf(a.y) << 16);
        pk[1] = (u32)f2bf(a.z) | ((u32)f2bf(a.w) << 16);
        pk[2] = (u32)f2bf(b.x) | ((u32)f2bf(b.y) << 16);
        pk[3] = (u32)f2bf(b.z) | ((u32)f2bf(b.w) << 16);
        *(uint4*)(dst + base) = *(uint4*)pk;
    } else {
        const uint4* s = (const uint4*)src;
        *(uint4*)(dst + base) = s[i];
    }
}

// ---------------- canonicalize small tensors -> fp32 ----------------
__global__ void k_canon_f(const void* __restrict__ src, float* __restrict__ dst, int n,
                          const int* __restrict__ flag){
    const int isf = *flag;
    int i = blockIdx.x * 256 + threadIdx.x;
    if (i < n){
        dst[i] = isf ? ((const float*)src)[i] : bf2f(((const u16*)src)[i]);
    }
}

// ---------------- QKV projection (VALU, unchanged this round) ----------------
__global__ __launch_bounds__(256, 2)
void k_proj(const u16* __restrict__ xc, const float* __restrict__ wq,
            const float* __restrict__ wkv, u16* __restrict__ qo, u16* __restrict__ kvo){
    __shared__ u16  xs[256][64];
    __shared__ float wt[64][132];
    const int t = threadIdx.x;
    const int b = blockIdx.z, h = blockIdx.y;
    const int px0 = blockIdx.x * 64;
    {
        const u32* xu = (const u32*)xc;
        const size_t rowbase = ((size_t)b * 4194304 + (size_t)h * 128 + px0) >> 1;
        u32* xsu = (u32*)xs;
        #pragma unroll
        for (int rep = 0; rep < 32; ++rep){
            int f = rep * 256 + t;
            int c = f >> 5, pu = f & 31;
            xsu[c * 32 + pu] = xu[rowbase + (size_t)c * 8192 + pu];
        }
    }
    const int og = t >> 4;
    const int pg = t & 15;

    for (int ot = 0; ot < 6; ++ot){
        const int o0 = ot * 128;
        float acc[8][4];
        #pragma unroll
        for (int j = 0; j < 8; ++j)
            #pragma unroll
            for (int p = 0; p < 4; ++p) acc[j][p] = 0.f;

        for (int kc = 0; kc < 4; ++kc){
            const int c0 = kc * 64;
            __syncthreads();
            #pragma unroll
            for (int i = 0; i < 32; ++i){
                int f = i * 256 + t;
                int cl = f & 63, ol = f >> 6;
                int o = o0 + ol;
                float wv;
                if (o < 256) wv = wq[o * 256 + c0 + cl];
                else         wv = wkv[(o - 256) * 256 + c0 + cl];
                wt[cl][ol] = wv;
            }
            __syncthreads();
            #pragma unroll 8
            for (int c = 0; c < 64; ++c){
                const float4 w0 = *(const float4*)&wt[c][og * 8];
                const float4 w1 = *(const float4*)&wt[c][og * 8 + 4];
                const uint2  xv = *(const uint2*)&xs[c0 + c][pg * 4];
                float wv[8] = {w0.x, w0.y, w0.z, w0.w, w1.x, w1.y, w1.z, w1.w};
                float xf[4] = {bflo(xv.x), bfhi(xv.x), bflo(xv.y), bfhi(xv.y)};
                #pragma unroll
                for (int j = 0; j < 8; ++j)
                    #pragma unroll
                    for (int p = 0; p < 4; ++p)
                        acc[j][p] = fmaf(wv[j], xf[p], acc[j][p]);
            }
        }
        #pragma unroll
        for (int p = 0; p < 4; ++p){
            const int px = px0 + pg * 4 + p;
            const size_t pix = (size_t)b * 16384 + (size_t)h * 128 + px;
            u32 pk[4];
            #pragma unroll
            for (int d = 0; d < 4; ++d)
                pk[d] = (u32)f2bf(acc[2*d][p]) | ((u32)f2bf(acc[2*d+1][p]) << 16);
            if (o0 < 256)
                *(uint4*)(qo + pix * 256 + o0 + og * 8) = *(uint4*)pk;
            else
                *(uint4*)(kvo + pix * 512 + (o0 - 256) + og * 8) = *(uint4*)pk;
        }
    }
}

// ---------------- MFMA halo attention ----------------
// Block = 512 thr = 8 waves; wave = one head. Key-tiles = window rows (14 tiles
// of 14 real + 2 masked keys). S^T = K.Q^T via mfma_16x16x32_bf16 (C layout:
// row=key=quad*4+reg, col=q=lane&15) so post-softmax P is ALREADY the B-frag
// of mfma_16x16x16bf16_1k for O'^T = V^T.P^T (same lane, reg i = key quad*4+i).
// Bias: bw[q][j]=q.rel_w[j-qy+13] lives in 16 regs (j=quad*4+r static under
// row tiling); bh[q][i] via per-head bf16 LDS table [21][64]; both computed by
// an MFMA pre-pass (REL.Q^T) reusing the Q B-frags. Masked keys (j>=14) get
// bias=-1e30 -> p=0 exactly; OOB rows stage K=V=0 but keep real bias, matching
// the reference's zero-pad-then-softmax semantics.
__global__ __launch_bounds__(512)
void k_attn(const u16* __restrict__ qc, const u16* __restrict__ kvc,
            const float* __restrict__ rh, const float* __restrict__ rw,
            u16* __restrict__ ctx){
    __shared__ u16 kvb[2][16][520];   // [buf][key j][512 ch + 8 pad]  33,280 B
    __shared__ u16 bht[8][21][64];    // per-head bias table (bf16)    21,504 B
    const int t = threadIdx.x;
    const int head = t >> 6, lane = t & 63;
    const int quad = lane >> 4, l15 = lane & 15;
    const int blk = blockIdx.x, b = blockIdx.y;
    const int r0 = (blk >> 4) * 8, c0 = (blk & 15) * 8;

    // ---- Q B-frags (per q n-tile): Q[q][head*32 + quad*8 .. +8] ----
    s16x8 qf[4];
    #pragma unroll
    for (int nt = 0; nt < 4; ++nt){
        int q = nt*16 + l15;
        size_t pix = (size_t)b*16384 + (size_t)(r0 + (q>>3))*128 + (c0 + (q&7));
        qf[nt] = *(const s16x8*)(qc + pix*256 + head*32 + quad*8);
    }

    // ---- staging geometry: thread covers (row j0, ch0) and (row j0+8, ch0) ----
    const int j0 = t >> 6;            // 0..7
    const int ch0 = (t & 63) * 8;     // 0..504 (u16 units; 16 B chunks)

    // ---- stage tile 0 into buf 0 ----
    {
        int hh = r0 - 3;
        bool vh = (hh >= 0 && hh < 128);
        int ww0 = c0 - 3 + j0, ww1 = ww0 + 8;
        uint4 v0 = make_uint4(0,0,0,0), v1 = make_uint4(0,0,0,0);
        if (vh && ww0 >= 0 && ww0 < 128)
            v0 = *(const uint4*)(kvc + ((size_t)b*16384 + (size_t)hh*128 + ww0)*512 + ch0);
        if (vh && (j0+8) < 14 && ww1 >= 0 && ww1 < 128)
            v1 = *(const uint4*)(kvc + ((size_t)b*16384 + (size_t)hh*128 + ww1)*512 + ch0);
        *(uint4*)&kvb[0][j0][ch0]   = v0;
        *(uint4*)&kvb[0][j0+8][ch0] = v1;
    }

    // ---- bias pre-pass: BW^T = RW.Q^T then BH^T = RH.Q^T (per head) ----
    float bwreg[4][4];
    {
        f32x4 d[2][4];
        // --- BW ---
        #pragma unroll
        for (int mt = 0; mt < 2; ++mt){
            int u = mt*16 + l15;
            s16x8 af;
            #pragma unroll
            for (int i2 = 0; i2 < 8; ++i2) af[i2] = 0;
            if (u <= 26){
                float4 a0 = *(const float4*)(rw + u*32 + quad*8);
                float4 a1 = *(const float4*)(rw + u*32 + quad*8 + 4);
                af[0]=(short)f2bf(a0.x); af[1]=(short)f2bf(a0.y);
                af[2]=(short)f2bf(a0.z); af[3]=(short)f2bf(a0.w);
                af[4]=(short)f2bf(a1.x); af[5]=(short)f2bf(a1.y);
                af[6]=(short)f2bf(a1.z); af[7]=(short)f2bf(a1.w);
            }
            #pragma unroll
            for (int nt = 0; nt < 4; ++nt){
                f32x4 z = {0.f,0.f,0.f,0.f};
                d[mt][nt] = __builtin_amdgcn_mfma_f32_16x16x32_bf16(af, qf[nt], z, 0,0,0);
            }
        }
        #pragma unroll
        for (int mt = 0; mt < 2; ++mt)
            #pragma unroll
            for (int nt = 0; nt < 4; ++nt)
                #pragma unroll
                for (int r = 0; r < 4; ++r){
                    int u = mt*16 + quad*4 + r;
                    if (u >= 6 && u <= 26)
                        bht[head][u-6][nt*16 + l15] = f2bf(d[mt][nt][r]);
                }
        __syncthreads();
        // read bw into registers (j = quad*4+r is tile-invariant under row tiling)
        #pragma unroll
        for (int nt = 0; nt < 4; ++nt){
            int q = nt*16 + l15, qy = l15 & 7;
            #pragma unroll
            for (int r = 0; r < 4; ++r){
                int j = quad*4 + r;
                bwreg[nt][r] = (j < 14) ? bf2f(bht[head][j + 7 - qy][q]) : -1e30f;
            }
        }
        __syncthreads();
        // --- BH (overwrites table) ---
        #pragma unroll
        for (int mt = 0; mt < 2; ++mt){
            int u = mt*16 + l15;
            s16x8 af;
            #pragma unroll
            for (int i2 = 0; i2 < 8; ++i2) af[i2] = 0;
            if (u <= 26){
                float4 a0 = *(const float4*)(rh + u*32 + quad*8);
                float4 a1 = *(const float4*)(rh + u*32 + quad*8 + 4);
                af[0]=(short)f2bf(a0.x); af[1]=(short)f2bf(a0.y);
                af[2]=(short)f2bf(a0.z); af[3]=(short)f2bf(a0.w);
                af[4]=(short)f2bf(a1.x); af[5]=(short)f2bf(a1.y);
                af[6]=(short)f2bf(a1.z); af[7]=(short)f2bf(a1.w);
            }
            #pragma unroll
            for (int nt = 0; nt < 4; ++nt){
                f32x4 z = {0.f,0.f,0.f,0.f};
                d[mt][nt] = __builtin_amdgcn_mfma_f32_16x16x32_bf16(af, qf[nt], z, 0,0,0);
            }
        }
        #pragma unroll
        for (int mt = 0; mt < 2; ++mt)
            #pragma unroll
            for (int nt = 0; nt < 4; ++nt)
                #pragma unroll
                for (int r = 0; r < 4; ++r){
                    int u = mt*16 + quad*4 + r;
                    if (u >= 6 && u <= 26)
                        bht[head][u-6][nt*16 + l15] = f2bf(d[mt][nt][r]);
                }
        // first loop barrier makes these visible before use
    }

    // ---- flash loop over 14 window rows ----
    float m_[4] = {-1e30f,-1e30f,-1e30f,-1e30f};
    float l_[4] = {0.f,0.f,0.f,0.f};
    f32x4 O[2][4];
    #pragma unroll
    for (int mt = 0; mt < 2; ++mt)
        #pragma unroll
        for (int nt = 0; nt < 4; ++nt){ f32x4 z = {0.f,0.f,0.f,0.f}; O[mt][nt] = z; }

    #pragma unroll 2
    for (int tile = 0; tile < 14; ++tile){
        // prefetch next tile to regs (in flight during compute)
        uint4 p0 = make_uint4(0,0,0,0), p1 = make_uint4(0,0,0,0);
        if (tile < 13){
            int hh = r0 - 3 + tile + 1;
            bool vh = (hh >= 0 && hh < 128);
            int ww0 = c0 - 3 + j0, ww1 = ww0 + 8;
            if (vh && ww0 >= 0 && ww0 < 128)
                p0 = *(const uint4*)(kvc + ((size_t)b*16384 + (size_t)hh*128 + ww0)*512 + ch0);
            if (vh && (j0+8) < 14 && ww1 >= 0 && ww1 < 128)
                p1 = *(const uint4*)(kvc + ((size_t)b*16384 + (size_t)hh*128 + ww1)*512 + ch0);
        }
        __syncthreads();   // buf[tile&1] staged; prior computes done
        const u16* kb = &kvb[tile & 1][0][0];

        // QK: S^T tiles (A = K rows, B = Q rows)
        s16x8 ak = *(const s16x8*)(kb + l15*520 + head*32 + quad*8);
        f32x4 sc[4];
        #pragma unroll
        for (int nt = 0; nt < 4; ++nt){
            f32x4 z = {0.f,0.f,0.f,0.f};
            sc[nt] = __builtin_amdgcn_mfma_f32_16x16x32_bf16(ak, qf[nt], z, 0,0,0);
        }
        // V A-frags: V^T[ch = mt*16+l15][key = quad*4+i]
        s16x4 av[2];
        #pragma unroll
        for (int mt = 0; mt < 2; ++mt)
            #pragma unroll
            for (int i = 0; i < 4; ++i)
                av[mt][i] = (short)kb[(quad*4 + i)*520 + 256 + head*32 + mt*16 + l15];

        // softmax (per q column) + PV
        #pragma unroll
        for (int nt = 0; nt < 4; ++nt){
            int q = nt*16 + l15;
            int qx = q >> 3;
            float bh = bf2f(bht[head][tile + 7 - qx][q]);
            float s0 = fmaf(sc[nt][0], QKSCALE, bwreg[nt][0] + bh);
            float s1 = fmaf(sc[nt][1], QKSCALE, bwreg[nt][1] + bh);
            float s2 = fmaf(sc[nt][2], QKSCALE, bwreg[nt][2] + bh);
            float s3 = fmaf(sc[nt][3], QKSCALE, bwreg[nt][3] + bh);
            float mx = fmaxf(fmaxf(s0, s1), fmaxf(s2, s3));
            mx = fmaxf(mx, __shfl_xor(mx, 16));
            mx = fmaxf(mx, __shfl_xor(mx, 32));
            float mn = fmaxf(m_[nt], mx);
            float al = __expf(m_[nt] - mn);
            m_[nt] = mn;
            float e0 = __expf(s0 - mn), e1 = __expf(s1 - mn);
            float e2 = __expf(s2 - mn), e3 = __expf(s3 - mn);
            float ls = (e0 + e1) + (e2 + e3);
            ls += __shfl_xor(ls, 16);
            ls += __shfl_xor(ls, 32);
            l_[nt] = fmaf(l_[nt], al, ls);
            s16x4 pp;
            pp[0] = (short)f2bf(e0); pp[1] = (short)f2bf(e1);
            pp[2] = (short)f2bf(e2); pp[3] = (short)f2bf(e3);
            #pragma unroll
            for (int mt = 0; mt < 2; ++mt){
                f32x4 o = O[mt][nt];
                o[0] *= al; o[1] *= al; o[2] *= al; o[3] *= al;
                O[mt][nt] = mfma16(av[mt], pp, o);
            }
        }
        // write prefetched tile into the other buffer
        if (tile < 13){
            int nb = (tile + 1) & 1;
            *(uint4*)&kvb[nb][j0][ch0]   = p0;
            *(uint4*)&kvb[nb][j0+8][ch0] = p1;
        }
    }

    // ---- epilogue: O'[ch][q] / l -> ctx[q][head*32+ch] ----
    #pragma unroll
    for (int nt = 0; nt < 4; ++nt){
        float inv = 1.f / l_[nt];
        int q = nt*16 + l15;
        size_t base = (((size_t)(b*256 + blk))*64 + q)*256 + head*32 + quad*4;
        #pragma unroll
        for (int mt = 0; mt < 2; ++mt){
            f32x4 o = O[mt][nt];
            u32 w0 = (u32)f2bf(o[0]*inv) | ((u32)f2bf(o[1]*inv) << 16);
            u32 w1 = (u32)f2bf(o[2]*inv) | ((u32)f2bf(o[3]*inv) << 16);
            uint2 st; st.x = w0; st.y = w1;
            *(uint2*)(ctx + base + mt*16) = st;
        }
    }
}

// ---------------- output projection + bias (VALU, unchanged this round) ----------------
__global__ __launch_bounds__(256, 2)
void k_out(const u16* __restrict__ ctx, const float* __restrict__ fcw,
           const float* __restrict__ fcb, void* __restrict__ outp,
           const int* __restrict__ flag){
    __shared__ u16  xs[256][68];
    __shared__ float wt[64][132];
    const int t = threadIdx.x;
    const int b = blockIdx.z, h = blockIdx.y;
    const int px0 = blockIdx.x * 64;
    {
        #pragma unroll
        for (int rep = 0; rep < 32; ++rep){
            int fu = rep * 256 + t;
            int pxl = fu >> 7, chu = fu & 127;
            int px = px0 + pxl;
            int blkid = (h >> 3) * 16 + (px >> 3);
            int qi = (h & 7) * 8 + (px & 7);
            u32 v = ((const u32*)ctx)[(((size_t)b * 256 + blkid) * 64 + qi) * 128 + chu];
            xs[2*chu][pxl]     = (u16)(v & 0xffffu);
            xs[2*chu + 1][pxl] = (u16)(v >> 16);
        }
    }
    const int og = t >> 4, pg = t & 15;
    const int isf32 = *flag;

    for (int ot = 0; ot < 2; ++ot){
        const int o0 = ot * 128;
        float acc[8][4];
        #pragma unroll
        for (int j = 0; j < 8; ++j)
            #pragma unroll
            for (int p = 0; p < 4; ++p) acc[j][p] = 0.f;

        for (int kc = 0; kc < 4; ++kc){
            const int c0 = kc * 64;
            __syncthreads();
            #pragma unroll
            for (int i = 0; i < 32; ++i){
                int f = i * 256 + t;
                int cl = f & 63, ol = f >> 6;
                wt[cl][ol] = fcw[(o0 + ol) * 256 + c0 + cl];
            }
            __syncthreads();
            #pragma unroll 8
            for (int c = 0; c < 64; ++c){
                const float4 w0 = *(const float4*)&wt[c][og * 8];
                const float4 w1 = *(const float4*)&wt[c][og * 8 + 4];
                const uint2  xv = *(const uint2*)&xs[c0 + c][pg * 4];
                float wv[8] = {w0.x, w0.y, w0.z, w0.w, w1.x, w1.y, w1.z, w1.w};
                float xf[4] = {bflo(xv.x), bfhi(xv.x), bflo(xv.y), bfhi(xv.y)};
                #pragma unroll
                for (int j = 0; j < 8; ++j)
                    #pragma unroll
                    for (int p = 0; p < 4; ++p)
                        acc[j][p] = fmaf(wv[j], xf[p], acc[j][p]);
            }
        }
        #pragma unroll
        for (int j = 0; j < 8; ++j){
            const int oo = o0 + og * 8 + j;
            const float bias = fcb[oo];
            const size_t obase = ((size_t)b * 256 + oo) * 16384 + (size_t)h * 128 + px0 + pg * 4;
            if (isf32){
                float4 v;
                v.x = acc[j][0] + bias; v.y = acc[j][1] + bias;
                v.z = acc[j][2] + bias; v.w = acc[j][3] + bias;
                *(float4*)((float*)outp + obase) = v;
            } else {
                u32 pk0 = (u32)f2bf(acc[j][0] + bias) | ((u32)f2bf(acc[j][1] + bias) << 16);
                u32 pk1 = (u32)f2bf(acc[j][2] + bias) | ((u32)f2bf(acc[j][3] + bias) << 16);
                uint2 v; v.x = pk0; v.y = pk1;
                *(uint2*)((u16*)outp + obase) = v;
            }
        }
    }
}

extern "C" void kernel_launch(void* const* d_in, const int* in_sizes, int n_in,
                              void* d_out, int out_size, void* d_ws, size_t ws_size,
                              hipStream_t stream){
    const void* x    = d_in[0];
    const void* wq   = d_in[1];
    const void* wkv  = d_in[2];
    const void* fcw  = d_in[3];
    const void* fcb  = d_in[4];
    const void* relh = d_in[5];
    const void* relw = d_in[6];

    char* ws = (char*)d_ws;
    u16*   xc   = (u16*)(ws + WS_XC);
    float* wqf  = (float*)(ws + WS_WQ);
    float* wkvf = (float*)(ws + WS_WKV);
    float* fcwf = (float*)(ws + WS_FCW);
    float* fcbf = (float*)(ws + WS_FCB);
    float* rhf  = (float*)(ws + WS_RH);
    float* rwf  = (float*)(ws + WS_RW);
    int*   flag = (int*)(ws + WS_FLAG);
    u16*   qb   = (u16*)(ws + WS_Q);
    u16*   kvb  = (u16*)(ws + WS_KV);
    u16*   ctxb = (u16*)(ws + WS_CTX);

    k_detect<<<1, 64, 0, stream>>>((const u16*)x, flag);
    k_canon_x<<<8192, 256, 0, stream>>>(x, xc, flag);
    k_canon_f<<<256, 256, 0, stream>>>(wq,   wqf,  65536,  flag);
    k_canon_f<<<512, 256, 0, stream>>>(wkv,  wkvf, 131072, flag);
    k_canon_f<<<256, 256, 0, stream>>>(fcw,  fcwf, 65536,  flag);
    k_canon_f<<<1,   256, 0, stream>>>(fcb,  fcbf, 256,    flag);
    k_canon_f<<<4,   256, 0, stream>>>(relh, rhf,  864,    flag);
    k_canon_f<<<4,   256, 0, stream>>>(relw, rwf,  864,    flag);

    dim3 gp(2, 128, 4);
    k_proj<<<gp, 256, 0, stream>>>(xc, wqf, wkvf, qb, kvb);
    dim3 ga(256, 4);
    k_attn<<<ga, 512, 0, stream>>>(qb, kvb, rhf, rwf, ctxb);
    dim3 go(2, 128, 4);
    k_out<<<go, 256, 0, stream>>>(ctxb, fcwf, fcbf, d_out, flag);
}

// Round 5
// 373.507 us; speedup vs baseline: 5.9472x; 2.7880x over previous
//
#include <hip/hip_runtime.h>
#include <hip/hip_bf16.h>
#include <stdint.h>

typedef unsigned short u16;
typedef unsigned int u32;

// ---- problem constants ----
#define HEADS  8
#define DH     32
#define BLK    8
#define HALO   3
#define WINSZ  14
#define QKSCALE 0.17677669529663689f   // 32^-0.5

// ---- workspace layout (bytes) ----
#define WS_XT   ((size_t)0)                    // xt bf16 [B*16384][256]: 33,554,432
#define WS_WB   ((size_t)33554432)             // w bf16 [768][256] (q,k,v): 393,216
#define WS_FCWB (WS_WB + 393216)               // fc_w bf16 [256][256]: 131,072
#define WS_FCB  (WS_FCWB + 131072)             // fc_b fp32: 1,024
#define WS_RH   (WS_FCB + 1024)                // rel_h fp32: 3,456
#define WS_RW   (WS_RH + 3456)                 // rel_w fp32: 3,456
#define WS_FLAG (WS_RW + 3456)                 // int flag
#define WS_Q    ((size_t)34611200)             // q bf16 [65536][256]: 33,554,432
#define WS_KV   (WS_Q + 33554432)              // kv bf16 [65536][512]: 67,108,864
#define WS_CTX  (WS_KV + 67108864)             // ctx bf16 [B*256 blk][64][256]: 33,554,432

typedef float f32x4 __attribute__((ext_vector_type(4)));
typedef short s16x8 __attribute__((ext_vector_type(8)));
typedef short s16x4 __attribute__((ext_vector_type(4)));

__device__ __forceinline__ float bflo(u32 u){ return __uint_as_float(u << 16); }
__device__ __forceinline__ float bfhi(u32 u){ return __uint_as_float(u & 0xffff0000u); }
__device__ __forceinline__ float bf2f(u16 h){ return __uint_as_float(((u32)h) << 16); }
__device__ __forceinline__ u16 f2bf(float f){
    u32 u = __float_as_uint(f);
    u32 r = (u + 0x7fffu + ((u >> 16) & 1u)) >> 16;   // RNE
    return (u16)r;
}

// NOTE: __has_builtin guards on amdgcn builtins must live inside
// __HIP_DEVICE_COMPILE__ — host pass picks the wrong branch otherwise (R3).
#if defined(__HIP_DEVICE_COMPILE__)
__device__ __forceinline__ f32x4 mfma16(s16x4 a, s16x4 b, f32x4 c){
    return __builtin_amdgcn_mfma_f32_16x16x16bf16_1k(a, b, c, 0, 0, 0);
}
#else
__device__ __forceinline__ f32x4 mfma16(s16x4 a, s16x4 b, f32x4 c){ return c; }
#endif

// ---------------- dtype detector ----------------
__global__ void k_detect(const u16* __restrict__ x, int* __restrict__ flag){
    int t = threadIdx.x;
    int wild = 0;
    for (int i = t; i < 1024; i += 64){
        u16 u = x[2*i];
        int ef = (u >> 7) & 0xff;
        if (ef >= 0x90) wild = 1;
    }
    int any = __any(wild);
    if (t == 0) *flag = any ? 1 : 0;
}

// ---------------- canonicalize + transpose x -> xt[pix][c] bf16 ----------------
// tile: 64 c x 64 pix per block via LDS
__global__ __launch_bounds__(256)
void k_canon_xt(const void* __restrict__ src, u16* __restrict__ dst,
                const int* __restrict__ flag){
    __shared__ u32 xsu[64][33];
    const int tile = blockIdx.x;                 // [b(4)][ct(4)][pt(256)]
    const int pt = tile & 255, ct = (tile >> 8) & 3, b = tile >> 10;
    const int pix0 = pt * 64, c0 = ct * 64;
    const int t = threadIdx.x;
    const int isf = *flag;
    if (isf){
        const float* s = (const float*)src;
        #pragma unroll
        for (int rep = 0; rep < 8; ++rep){
            int f = rep * 256 + t;
            int c = f >> 5, pu = f & 31;
            const float2 v = *(const float2*)(s + ((size_t)b*256 + c0 + c)*16384 + pix0 + pu*2);
            xsu[c][pu] = (u32)f2bf(v.x) | ((u32)f2bf(v.y) << 16);
        }
    } else {
        const u32* s = (const u32*)src;
        #pragma unroll
        for (int rep = 0; rep < 8; ++rep){
            int f = rep * 256 + t;
            int c = f >> 5, pu = f & 31;
            xsu[c][pu] = s[(((size_t)b*256 + c0 + c)*16384 + pix0)/2 + pu];
        }
    }
    __syncthreads();
    #pragma unroll
    for (int rep = 0; rep < 2; ++rep){
        int f = rep * 256 + t;                   // 512 = 64 pix x 8 c-groups
        int pix = f >> 3, cu8 = f & 7;
        u32 pk[4];
        #pragma unroll
        for (int d = 0; d < 4; ++d){
            u32 a = xsu[cu8*8 + 2*d][pix >> 1];
            u32 bb = xsu[cu8*8 + 2*d + 1][pix >> 1];
            u16 ha = (pix & 1) ? (u16)(a >> 16) : (u16)(a & 0xffffu);
            u16 hb = (pix & 1) ? (u16)(bb >> 16) : (u16)(bb & 0xffffu);
            pk[d] = (u32)ha | ((u32)hb << 16);
        }
        *(uint4*)(dst + ((size_t)b*16384 + pix0 + pix)*256 + c0 + cu8*8) = *(uint4*)pk;
    }
}

// ---------------- canonicalize weights -> bf16 [o][c] ----------------
__global__ void k_canon_w(const void* __restrict__ wq, const void* __restrict__ wkv,
                          const void* __restrict__ fcw, u16* __restrict__ wb,
                          u16* __restrict__ fcwb, const int* __restrict__ flag){
    const int isf = *flag;
    int i = blockIdx.x * 256 + threadIdx.x;      // 262144 total
    if (i < 196608){
        int o = i >> 8, c = i & 255;
        const void* src = (o < 256) ? wq : wkv;
        int oo = (o < 256) ? o : o - 256;
        float v = isf ? ((const float*)src)[oo*256 + c] : bf2f(((const u16*)src)[oo*256 + c]);
        wb[i] = f2bf(v);
    } else {
        int j = i - 196608;
        float v = isf ? ((const float*)fcw)[j] : bf2f(((const u16*)fcw)[j]);
        fcwb[j] = f2bf(v);
    }
}

// ---------------- canonicalize small tensors -> fp32 ----------------
__global__ void k_canon_f(const void* __restrict__ src, float* __restrict__ dst, int n,
                          const int* __restrict__ flag){
    const int isf = *flag;
    int i = blockIdx.x * 256 + threadIdx.x;
    if (i < n){
        dst[i] = isf ? ((const float*)src)[i] : bf2f(((const u16*)src)[i]);
    }
}

// ---------------- MFMA QKV projection ----------------
// No LDS. Wave holds 32 pixels (2 B-frag n-tiles of XT rows, 64 VGPRs) and
// loops 48 o-tiles: A-frags = W rows from global (L2-hot), 16 MFMAs, store.
// D[row = o = quad*4+r][col = pix = l15] -> uint2 (4 consecutive o) per lane
// into q[pix][256] / kv[pix][512] (layouts k_attn consumes unchanged).
__global__ __launch_bounds__(256)
void k_proj(const u16* __restrict__ xt, const u16* __restrict__ wb,
            u16* __restrict__ qo, u16* __restrict__ kvo){
    const int t = threadIdx.x;
    const int wave = t >> 6, lane = t & 63;
    const int quad = lane >> 4, l15 = lane & 15;
    const int p0 = blockIdx.x * 128 + wave * 32;

    s16x8 bf[2][8];
    #pragma unroll
    for (int nt = 0; nt < 2; ++nt){
        const u16* row = xt + (size_t)(p0 + nt*16 + l15) * 256 + quad * 8;
        #pragma unroll
        for (int kc = 0; kc < 8; ++kc)
            bf[nt][kc] = *(const s16x8*)(row + kc * 32);
    }

    for (int ot = 0; ot < 48; ++ot){
        const u16* arow = wb + (size_t)(ot*16 + l15) * 256 + quad * 8;
        s16x8 af[8];
        #pragma unroll
        for (int kc = 0; kc < 8; ++kc)
            af[kc] = *(const s16x8*)(arow + kc * 32);
        f32x4 acc0 = {0.f,0.f,0.f,0.f}, acc1 = {0.f,0.f,0.f,0.f};
        #pragma unroll
        for (int kc = 0; kc < 8; ++kc){
            acc0 = __builtin_amdgcn_mfma_f32_16x16x32_bf16(af[kc], bf[0][kc], acc0, 0,0,0);
            acc1 = __builtin_amdgcn_mfma_f32_16x16x32_bf16(af[kc], bf[1][kc], acc1, 0,0,0);
        }
        const int o = ot*16 + quad*4;
        #pragma unroll
        for (int nt = 0; nt < 2; ++nt){
            const f32x4 a = nt ? acc1 : acc0;
            const size_t pix = p0 + nt*16 + l15;
            uint2 st;
            st.x = (u32)f2bf(a[0]) | ((u32)f2bf(a[1]) << 16);
            st.y = (u32)f2bf(a[2]) | ((u32)f2bf(a[3]) << 16);
            if (ot < 16) *(uint2*)(qo  + pix*256 + o)        = st;
            else         *(uint2*)(kvo + pix*512 + (o - 256)) = st;
        }
    }
}

// ---------------- MFMA halo attention (unchanged from R4) ----------------
__global__ __launch_bounds__(512)
void k_attn(const u16* __restrict__ qc, const u16* __restrict__ kvc,
            const float* __restrict__ rh, const float* __restrict__ rw,
            u16* __restrict__ ctx){
    __shared__ u16 kvb[2][16][520];
    __shared__ u16 bht[8][21][64];
    const int t = threadIdx.x;
    const int head = t >> 6, lane = t & 63;
    const int quad = lane >> 4, l15 = lane & 15;
    const int blk = blockIdx.x, b = blockIdx.y;
    const int r0 = (blk >> 4) * 8, c0 = (blk & 15) * 8;

    s16x8 qf[4];
    #pragma unroll
    for (int nt = 0; nt < 4; ++nt){
        int q = nt*16 + l15;
        size_t pix = (size_t)b*16384 + (size_t)(r0 + (q>>3))*128 + (c0 + (q&7));
        qf[nt] = *(const s16x8*)(qc + pix*256 + head*32 + quad*8);
    }

    const int j0 = t >> 6;
    const int ch0 = (t & 63) * 8;

    {
        int hh = r0 - 3;
        bool vh = (hh >= 0 && hh < 128);
        int ww0 = c0 - 3 + j0, ww1 = ww0 + 8;
        uint4 v0 = make_uint4(0,0,0,0), v1 = make_uint4(0,0,0,0);
        if (vh && ww0 >= 0 && ww0 < 128)
            v0 = *(const uint4*)(kvc + ((size_t)b*16384 + (size_t)hh*128 + ww0)*512 + ch0);
        if (vh && (j0+8) < 14 && ww1 >= 0 && ww1 < 128)
            v1 = *(const uint4*)(kvc + ((size_t)b*16384 + (size_t)hh*128 + ww1)*512 + ch0);
        *(uint4*)&kvb[0][j0][ch0]   = v0;
        *(uint4*)&kvb[0][j0+8][ch0] = v1;
    }

    float bwreg[4][4];
    {
        f32x4 d[2][4];
        #pragma unroll
        for (int mt = 0; mt < 2; ++mt){
            int u = mt*16 + l15;
            s16x8 af;
            #pragma unroll
            for (int i2 = 0; i2 < 8; ++i2) af[i2] = 0;
            if (u <= 26){
                float4 a0 = *(const float4*)(rw + u*32 + quad*8);
                float4 a1 = *(const float4*)(rw + u*32 + quad*8 + 4);
                af[0]=(short)f2bf(a0.x); af[1]=(short)f2bf(a0.y);
                af[2]=(short)f2bf(a0.z); af[3]=(short)f2bf(a0.w);
                af[4]=(short)f2bf(a1.x); af[5]=(short)f2bf(a1.y);
                af[6]=(short)f2bf(a1.z); af[7]=(short)f2bf(a1.w);
            }
            #pragma unroll
            for (int nt = 0; nt < 4; ++nt){
                f32x4 z = {0.f,0.f,0.f,0.f};
                d[mt][nt] = __builtin_amdgcn_mfma_f32_16x16x32_bf16(af, qf[nt], z, 0,0,0);
            }
        }
        #pragma unroll
        for (int mt = 0; mt < 2; ++mt)
            #pragma unroll
            for (int nt = 0; nt < 4; ++nt)
                #pragma unroll
                for (int r = 0; r < 4; ++r){
                    int u = mt*16 + quad*4 + r;
                    if (u >= 6 && u <= 26)
                        bht[head][u-6][nt*16 + l15] = f2bf(d[mt][nt][r]);
                }
        __syncthreads();
        #pragma unroll
        for (int nt = 0; nt < 4; ++nt){
            int q = nt*16 + l15, qy = l15 & 7;
            #pragma unroll
            for (int r = 0; r < 4; ++r){
                int j = quad*4 + r;
                bwreg[nt][r] = (j < 14) ? bf2f(bht[head][j + 7 - qy][q]) : -1e30f;
            }
        }
        __syncthreads();
        #pragma unroll
        for (int mt = 0; mt < 2; ++mt){
            int u = mt*16 + l15;
            s16x8 af;
            #pragma unroll
            for (int i2 = 0; i2 < 8; ++i2) af[i2] = 0;
            if (u <= 26){
                float4 a0 = *(const float4*)(rh + u*32 + quad*8);
                float4 a1 = *(const float4*)(rh + u*32 + quad*8 + 4);
                af[0]=(short)f2bf(a0.x); af[1]=(short)f2bf(a0.y);
                af[2]=(short)f2bf(a0.z); af[3]=(short)f2bf(a0.w);
                af[4]=(short)f2bf(a1.x); af[5]=(short)f2bf(a1.y);
                af[6]=(short)f2bf(a1.z); af[7]=(short)f2bf(a1.w);
            }
            #pragma unroll
            for (int nt = 0; nt < 4; ++nt){
                f32x4 z = {0.f,0.f,0.f,0.f};
                d[mt][nt] = __builtin_amdgcn_mfma_f32_16x16x32_bf16(af, qf[nt], z, 0,0,0);
            }
        }
        #pragma unroll
        for (int mt = 0; mt < 2; ++mt)
            #pragma unroll
            for (int nt = 0; nt < 4; ++nt)
                #pragma unroll
                for (int r = 0; r < 4; ++r){
                    int u = mt*16 + quad*4 + r;
                    if (u >= 6 && u <= 26)
                        bht[head][u-6][nt*16 + l15] = f2bf(d[mt][nt][r]);
                }
    }

    float m_[4] = {-1e30f,-1e30f,-1e30f,-1e30f};
    float l_[4] = {0.f,0.f,0.f,0.f};
    f32x4 O[2][4];
    #pragma unroll
    for (int mt = 0; mt < 2; ++mt)
        #pragma unroll
        for (int nt = 0; nt < 4; ++nt){ f32x4 z = {0.f,0.f,0.f,0.f}; O[mt][nt] = z; }

    #pragma unroll 2
    for (int tile = 0; tile < 14; ++tile){
        uint4 p0 = make_uint4(0,0,0,0), p1 = make_uint4(0,0,0,0);
        if (tile < 13){
            int hh = r0 - 3 + tile + 1;
            bool vh = (hh >= 0 && hh < 128);
            int ww0 = c0 - 3 + j0, ww1 = ww0 + 8;
            if (vh && ww0 >= 0 && ww0 < 128)
                p0 = *(const uint4*)(kvc + ((size_t)b*16384 + (size_t)hh*128 + ww0)*512 + ch0);
            if (vh && (j0+8) < 14 && ww1 >= 0 && ww1 < 128)
                p1 = *(const uint4*)(kvc + ((size_t)b*16384 + (size_t)hh*128 + ww1)*512 + ch0);
        }
        __syncthreads();
        const u16* kb = &kvb[tile & 1][0][0];

        s16x8 ak = *(const s16x8*)(kb + l15*520 + head*32 + quad*8);
        f32x4 sc[4];
        #pragma unroll
        for (int nt = 0; nt < 4; ++nt){
            f32x4 z = {0.f,0.f,0.f,0.f};
            sc[nt] = __builtin_amdgcn_mfma_f32_16x16x32_bf16(ak, qf[nt], z, 0,0,0);
        }
        s16x4 av[2];
        #pragma unroll
        for (int mt = 0; mt < 2; ++mt)
            #pragma unroll
            for (int i = 0; i < 4; ++i)
                av[mt][i] = (short)kb[(quad*4 + i)*520 + 256 + head*32 + mt*16 + l15];

        #pragma unroll
        for (int nt = 0; nt < 4; ++nt){
            int q = nt*16 + l15;
            int qx = q >> 3;
            float bh = bf2f(bht[head][tile + 7 - qx][q]);
            float s0 = fmaf(sc[nt][0], QKSCALE, bwreg[nt][0] + bh);
            float s1 = fmaf(sc[nt][1], QKSCALE, bwreg[nt][1] + bh);
            float s2 = fmaf(sc[nt][2], QKSCALE, bwreg[nt][2] + bh);
            float s3 = fmaf(sc[nt][3], QKSCALE, bwreg[nt][3] + bh);
            float mx = fmaxf(fmaxf(s0, s1), fmaxf(s2, s3));
            mx = fmaxf(mx, __shfl_xor(mx, 16));
            mx = fmaxf(mx, __shfl_xor(mx, 32));
            float mn = fmaxf(m_[nt], mx);
            float al = __expf(m_[nt] - mn);
            m_[nt] = mn;
            float e0 = __expf(s0 - mn), e1 = __expf(s1 - mn);
            float e2 = __expf(s2 - mn), e3 = __expf(s3 - mn);
            float ls = (e0 + e1) + (e2 + e3);
            ls += __shfl_xor(ls, 16);
            ls += __shfl_xor(ls, 32);
            l_[nt] = fmaf(l_[nt], al, ls);
            s16x4 pp;
            pp[0] = (short)f2bf(e0); pp[1] = (short)f2bf(e1);
            pp[2] = (short)f2bf(e2); pp[3] = (short)f2bf(e3);
            #pragma unroll
            for (int mt = 0; mt < 2; ++mt){
                f32x4 o = O[mt][nt];
                o[0] *= al; o[1] *= al; o[2] *= al; o[3] *= al;
                O[mt][nt] = mfma16(av[mt], pp, o);
            }
        }
        if (tile < 13){
            int nb = (tile + 1) & 1;
            *(uint4*)&kvb[nb][j0][ch0]   = p0;
            *(uint4*)&kvb[nb][j0+8][ch0] = p1;
        }
    }

    #pragma unroll
    for (int nt = 0; nt < 4; ++nt){
        float inv = 1.f / l_[nt];
        int q = nt*16 + l15;
        size_t base = (((size_t)(b*256 + blk))*64 + q)*256 + head*32 + quad*4;
        #pragma unroll
        for (int mt = 0; mt < 2; ++mt){
            f32x4 o = O[mt][nt];
            u32 w0 = (u32)f2bf(o[0]*inv) | ((u32)f2bf(o[1]*inv) << 16);
            u32 w1 = (u32)f2bf(o[2]*inv) | ((u32)f2bf(o[3]*inv) << 16);
            uint2 st; st.x = w0; st.y = w1;
            *(uint2*)(ctx + base + mt*16) = st;
        }
    }
}

// ---------------- MFMA output projection + bias ----------------
// A = ctx rows (pixels), B = fc_w rows (o). D[row = pix quad*4+r][col = o l15]
// -> lane stores 4 CONSECUTIVE pixels at fixed o: coalesced into out[b][o][pix].
__global__ __launch_bounds__(256)
void k_out(const u16* __restrict__ ctx, const u16* __restrict__ fcwb,
           const float* __restrict__ fcb, void* __restrict__ outp,
           const int* __restrict__ flag){
    const int t = threadIdx.x;
    const int wave = t >> 6, lane = t & 63;
    const int quad = lane >> 4, l15 = lane & 15;
    const int p0 = blockIdx.x * 128 + wave * 32;
    const int b = p0 >> 14;
    const int h = (p0 >> 7) & 127, w0 = p0 & 127;
    const int isf32 = *flag;

    s16x8 af[2][8];
    #pragma unroll
    for (int mt = 0; mt < 2; ++mt){
        int w = w0 + mt*16 + l15;
        int blkid = (h >> 3) * 16 + (w >> 3);
        int qi = (h & 7) * 8 + (w & 7);
        const u16* row = ctx + ((size_t)(b*256 + blkid)*64 + qi) * 256 + quad * 8;
        #pragma unroll
        for (int kc = 0; kc < 8; ++kc)
            af[mt][kc] = *(const s16x8*)(row + kc * 32);
    }

    for (int ot = 0; ot < 16; ++ot){
        const u16* brow = fcwb + (size_t)(ot*16 + l15) * 256 + quad * 8;
        s16x8 bfr[8];
        #pragma unroll
        for (int kc = 0; kc < 8; ++kc)
            bfr[kc] = *(const s16x8*)(brow + kc * 32);
        f32x4 acc0 = {0.f,0.f,0.f,0.f}, acc1 = {0.f,0.f,0.f,0.f};
        #pragma unroll
        for (int kc = 0; kc < 8; ++kc){
            acc0 = __builtin_amdgcn_mfma_f32_16x16x32_bf16(af[0][kc], bfr[kc], acc0, 0,0,0);
            acc1 = __builtin_amdgcn_mfma_f32_16x16x32_bf16(af[1][kc], bfr[kc], acc1, 0,0,0);
        }
        const float bias = fcb[ot*16 + l15];
        #pragma unroll
        for (int mt = 0; mt < 2; ++mt){
            const f32x4 a = mt ? acc1 : acc0;
            const int wv = w0 + mt*16 + quad*4;
            const size_t obase = (size_t)b*4194304 + (size_t)(ot*16 + l15)*16384
                               + (size_t)h*128 + wv;
            if (isf32){
                float4 v;
                v.x = a[0] + bias; v.y = a[1] + bias;
                v.z = a[2] + bias; v.w = a[3] + bias;
                *(float4*)((float*)outp + obase) = v;
            } else {
                uint2 v;
                v.x = (u32)f2bf(a[0] + bias) | ((u32)f2bf(a[1] + bias) << 16);
                v.y = (u32)f2bf(a[2] + bias) | ((u32)f2bf(a[3] + bias) << 16);
                *(uint2*)((u16*)outp + obase) = v;
            }
        }
    }
}

extern "C" void kernel_launch(void* const* d_in, const int* in_sizes, int n_in,
                              void* d_out, int out_size, void* d_ws, size_t ws_size,
                              hipStream_t stream){
    const void* x    = d_in[0];
    const void* wq   = d_in[1];
    const void* wkv  = d_in[2];
    const void* fcw  = d_in[3];
    const void* fcb  = d_in[4];
    const void* relh = d_in[5];
    const void* relw = d_in[6];

    char* ws = (char*)d_ws;
    u16*   xt   = (u16*)(ws + WS_XT);
    u16*   wb   = (u16*)(ws + WS_WB);
    u16*   fcwb = (u16*)(ws + WS_FCWB);
    float* fcbf = (float*)(ws + WS_FCB);
    float* rhf  = (float*)(ws + WS_RH);
    float* rwf  = (float*)(ws + WS_RW);
    int*   flag = (int*)(ws + WS_FLAG);
    u16*   qb   = (u16*)(ws + WS_Q);
    u16*   kvb  = (u16*)(ws + WS_KV);
    u16*   ctxb = (u16*)(ws + WS_CTX);

    k_detect<<<1, 64, 0, stream>>>((const u16*)x, flag);
    k_canon_xt<<<4096, 256, 0, stream>>>(x, xt, flag);
    k_canon_w<<<1024, 256, 0, stream>>>(wq, wkv, fcw, wb, fcwb, flag);
    k_canon_f<<<1, 256, 0, stream>>>(fcb,  fcbf, 256, flag);
    k_canon_f<<<4, 256, 0, stream>>>(relh, rhf,  864, flag);
    k_canon_f<<<4, 256, 0, stream>>>(relw, rwf,  864, flag);

    k_proj<<<512, 256, 0, stream>>>(xt, wb, qb, kvb);
    dim3 ga(256, 4);
    k_attn<<<ga, 512, 0, stream>>>(qb, kvb, rhf, rwf, ctxb);
    k_out<<<512, 256, 0, stream>>>(ctxb, fcwb, fcbf, d_out, flag);
}